// Round 1
// baseline (244.493 us; speedup 1.0000x reference)
//
#include <hip/hip_runtime.h>
#include <math.h>

#define NU 32768
#define NI 16384
#define DH 64
#define KK 50
#define SP 51   // mailT row stride (odd -> conflict-free both orientations)

// ---------------------------------------------------------------------------
// One-time parameter reshuffles:
//  gate [64][128] -> gT packed for float4 reads: gT[(j>>2)*256 + d*4 + (j&3)]
//  te   [50][64]  -> tT[d*50 + r]  (transposed, coalesced over rank r)
// ---------------------------------------------------------------------------
__global__ __launch_bounds__(256) void prep_kernel(
    const float* __restrict__ gate_u, const float* __restrict__ gate_i,
    const float* __restrict__ u_te,   const float* __restrict__ i_te,
    float* __restrict__ gT_u, float* __restrict__ gT_i,
    float* __restrict__ tT_u, float* __restrict__ tT_i)
{
    int t = blockIdx.x * 256 + threadIdx.x;
    int stride = gridDim.x * 256;
    for (int i = t; i < DH * 2 * DH; i += stride) {
        int d = i >> 7, j = i & 127;
        int dst = (j >> 2) * 256 + d * 4 + (j & 3);
        gT_u[dst] = gate_u[i];
        gT_i[dst] = gate_i[i];
    }
    for (int i = t; i < KK * DH; i += stride) {
        int r = i >> 6, d = i & 63;
        tT_u[d * KK + r] = u_te[i];
        tT_i[d * KK + r] = i_te[i];
    }
}

// ---------------------------------------------------------------------------
// h = feat @ W.T   (h[n][d] = sum_k feat[n][k] * W[d][k])
// W staged in LDS [64][65] (pad -> (lane+k)%32 banks, conflict-free).
// feat row broadcast via __shfl (compiles to v_readlane, no barriers).
// ---------------------------------------------------------------------------
__global__ __launch_bounds__(256) void proj_kernel(
    const float* __restrict__ feat, const float* __restrict__ W,
    float* __restrict__ h, int N)
{
    __shared__ float Wl[64 * 65];
    const int lane = threadIdx.x & 63;
    const int w = threadIdx.x >> 6;
    for (int i = threadIdx.x; i < 4096; i += 256)
        Wl[(i >> 6) * 65 + (i & 63)] = W[i];
    __syncthreads();
    int row0 = blockIdx.x * 32 + w * 8;
    for (int r = 0; r < 8; ++r) {
        int n = row0 + r;
        float fv = feat[n * DH + lane];
        float acc = 0.f;
        #pragma unroll
        for (int k = 0; k < DH; ++k)
            acc = fmaf(__shfl(fv, k), Wl[lane * 65 + k], acc);
        h[n * DH + lane] = acc;
    }
}

// ---------------------------------------------------------------------------
// Per-node mailbox attention. One wave (64 lanes) per node.
// mailT[d][k] in LDS, stride 51. Dots: lane=k (serial over d).
// Weighted sums + gate: lane=d (serial over k/j).
// ---------------------------------------------------------------------------
__global__ __launch_bounds__(64) void agg_kernel(
    const float* __restrict__ h_src,    // mail source embeddings
    const float* __restrict__ h_dst,    // destination embeddings
    const float* __restrict__ feat_dst, // pre-projection features (residual)
    const int*   __restrict__ nbr,      // [N][KK]
    const int*   __restrict__ times,    // [N][KK]
    const float* __restrict__ teT,      // [64][50]
    const float* __restrict__ te_k,     // [50][64]
    const float* __restrict__ gateT4,   // packed gate
    float* __restrict__ out)
{
    __shared__ float mailT[DH * SP];
    __shared__ float dsth[DH];
    __shared__ float sle[DH];
    __shared__ float cc[2 * DH];
    __shared__ float tp[KK];
    __shared__ float al[KK];
    __shared__ float al1[KK];
    __shared__ int   st[KK];
    __shared__ int   snb[KK];
    __shared__ int   sro[KK];

    const int n = blockIdx.x;
    const int lane = threadIdx.x;

    int my_t = 0;
    if (lane < KK) {
        my_t = times[n * KK + lane];
        st[lane]  = my_t;
        snb[lane] = nbr[n * KK + lane];
    }
    dsth[lane] = h_dst[n * DH + lane];
    __syncthreads();

    // gather mail rows (coalesced 256B loads), store transposed
    #pragma unroll
    for (int k = 0; k < KK; ++k)
        mailT[lane * SP + k] = h_src[snb[k] * DH + lane];

    // stable ascending ranks -> re_order = KK-1-rank (matches argsort(argsort))
    if (lane < KK) {
        int rank = 0;
        for (int j = 0; j < KK; ++j) {
            int tj = st[j];
            rank += (tj < my_t || (tj == my_t && j < lane)) ? 1 : 0;
        }
        sro[lane] = KK - 1 - rank;
    }

    // tp[r] = dot(te[r], dst_h)  (lane=r, coalesced teT reads)
    if (lane < KK) {
        float acc = 0.f;
        #pragma unroll
        for (int d = 0; d < DH; ++d)
            acc = fmaf(teT[d * KK + lane], dsth[d], acc);
        tp[lane] = acc;
    }

    // last = first index of max time (packed-key max reduce)
    int key = (lane < KK) ? ((my_t << 6) | (63 - lane)) : (int)0x80000000;
    #pragma unroll
    for (int off = 32; off >= 1; off >>= 1) {
        int o = __shfl_xor(key, off);
        key = key > o ? key : o;
    }
    const int last = 63 - (key & 63);

    __syncthreads();

    // ---- long-term attention scores + softmax (lane = k) ----
    float e = -INFINITY;
    if (lane < KK) {
        float acc = 0.f;
        #pragma unroll
        for (int d = 0; d < DH; ++d)
            acc = fmaf(mailT[d * SP + lane], dsth[d], acc);
        e = (acc + tp[sro[lane]]) * 0.125f;
    }
    float m = e;
    #pragma unroll
    for (int off = 32; off >= 1; off >>= 1)
        m = fmaxf(m, __shfl_xor(m, off));
    float p = (lane < KK) ? __expf(e - m) : 0.f;
    float s = p;
    #pragma unroll
    for (int off = 32; off >= 1; off >>= 1)
        s += __shfl_xor(s, off);
    if (lane < KK) al[lane] = p / s;

    // last_em broadcast buffer
    sle[lane] = mailT[lane * SP + last];
    __syncthreads();

    // ---- short-term attention scores + softmax (lane = k) ----
    float e1 = -INFINITY;
    if (lane < KK) {
        float acc = 0.f;
        #pragma unroll
        for (int d = 0; d < DH; ++d)
            acc = fmaf(mailT[d * SP + lane], sle[d], acc);
        e1 = acc * 0.125f;
    }
    float m1 = e1;
    #pragma unroll
    for (int off = 32; off >= 1; off >>= 1)
        m1 = fmaxf(m1, __shfl_xor(m1, off));
    float p1 = (lane < KK) ? __expf(e1 - m1) : 0.f;
    float s1 = p1;
    #pragma unroll
    for (int off = 32; off >= 1; off >>= 1)
        s1 += __shfl_xor(s1, off);
    if (lane < KK) al1[lane] = p1 / s1;
    __syncthreads();

    // ---- weighted sums (lane = d) ----
    float hl = 0.f, hs = 0.f;
    #pragma unroll
    for (int k = 0; k < KK; ++k) {
        float mv = mailT[lane * SP + k];
        float a  = al[k];
        float a1 = al1[k];
        hl = fmaf(a, mv + te_k[sro[k] * DH + lane], hl);
        hs = fmaf(a1, mv, hs);
    }
    cc[lane] = hl;
    cc[DH + lane] = hs;
    __syncthreads();

    // ---- gated output + residual + ELU ----
    float g = 0.f;
    const float4* g4 = (const float4*)gateT4;
    #pragma unroll
    for (int jb = 0; jb < 32; ++jb) {
        float4 gv = g4[jb * 64 + lane];
        g = fmaf(gv.x, cc[jb * 4 + 0], g);
        g = fmaf(gv.y, cc[jb * 4 + 1], g);
        g = fmaf(gv.z, cc[jb * 4 + 2], g);
        g = fmaf(gv.w, cc[jb * 4 + 3], g);
    }
    float x = g + feat_dst[n * DH + lane];
    out[n * DH + lane] = x > 0.f ? x : expm1f(x);
}

extern "C" void kernel_launch(void* const* d_in, const int* in_sizes, int n_in,
                              void* d_out, int out_size, void* d_ws, size_t ws_size,
                              hipStream_t stream) {
    const float* user_feat = (const float*)d_in[0];
    const float* item_feat = (const float*)d_in[1];
    const float* W_user    = (const float*)d_in[2];
    const float* W_item    = (const float*)d_in[3];
    const float* gate_u    = (const float*)d_in[4];
    const float* gate_i    = (const float*)d_in[5];
    const float* u_te      = (const float*)d_in[6];
    const float* u_te_k    = (const float*)d_in[7];
    const float* i_te      = (const float*)d_in[8];
    const float* i_te_k    = (const float*)d_in[9];
    const int*   user_nbr  = (const int*)d_in[10];
    const int*   item_nbr  = (const int*)d_in[11];
    const int*   user_time = (const int*)d_in[12];
    const int*   item_time = (const int*)d_in[13];

    float* ws     = (float*)d_ws;
    float* user_h = ws;                      // NU*64
    float* item_h = user_h + NU * DH;        // NI*64
    float* gT_u   = item_h + NI * DH;        // 8192
    float* gT_i   = gT_u + DH * 2 * DH;      // 8192
    float* tT_u   = gT_i + DH * 2 * DH;      // 3200
    float* tT_i   = tT_u + KK * DH;          // 3200

    float* user_out = (float*)d_out;
    float* item_out = user_out + NU * DH;

    hipLaunchKernelGGL(prep_kernel, dim3(64), dim3(256), 0, stream,
                       gate_u, gate_i, u_te, i_te, gT_u, gT_i, tT_u, tT_i);
    hipLaunchKernelGGL(proj_kernel, dim3(NU / 32), dim3(256), 0, stream,
                       user_feat, W_user, user_h, NU);
    hipLaunchKernelGGL(proj_kernel, dim3(NI / 32), dim3(256), 0, stream,
                       item_feat, W_item, item_h, NI);
    hipLaunchKernelGGL(agg_kernel, dim3(NI), dim3(64), 0, stream,
                       user_h, item_h, item_feat, item_nbr, item_time,
                       tT_i, i_te_k, gT_i, item_out);
    hipLaunchKernelGGL(agg_kernel, dim3(NU), dim3(64), 0, stream,
                       item_h, user_h, user_feat, user_nbr, user_time,
                       tT_u, u_te_k, gT_u, user_out);
}

// Round 2
// 177.869 us; speedup vs baseline: 1.3746x; 1.3746x over previous
//
#include <hip/hip_runtime.h>
#include <math.h>

#define NU 32768
#define NI 16384
#define DH 64
#define KK 50

typedef unsigned short ushort_t;
typedef unsigned int uint32_t_;

__device__ __forceinline__ float bflo(unsigned int u) { return __uint_as_float(u << 16); }
__device__ __forceinline__ float bfhi(unsigned int u) { return __uint_as_float(u & 0xffff0000u); }

// ---------------------------------------------------------------------------
// prep: gate pack (float4 layout) + teQ pack (tp matvec layout)
//   gT[(j>>2)*256 + d*4 + (j&3)] = gate[d][j]
//   teQ[(d4*50 + r)*4 + c]       = te[r][d4*4 + c]
// ---------------------------------------------------------------------------
__global__ __launch_bounds__(256) void prep_kernel(
    const float* __restrict__ gate_u, const float* __restrict__ gate_i,
    const float* __restrict__ u_te,   const float* __restrict__ i_te,
    float* __restrict__ gT_u, float* __restrict__ gT_i,
    float* __restrict__ teQ_u, float* __restrict__ teQ_i)
{
    int t = blockIdx.x * 256 + threadIdx.x;
    int stride = gridDim.x * 256;
    for (int i = t; i < DH * 2 * DH; i += stride) {
        int d = i >> 7, j = i & 127;
        int dst = (j >> 2) * 256 + d * 4 + (j & 3);
        gT_u[dst] = gate_u[i];
        gT_i[dst] = gate_i[i];
    }
    for (int i = t; i < 16 * KK * 4; i += stride) {
        int c = i & 3, rest = i >> 2;
        int r = rest % KK, d4 = rest / KK;
        teQ_u[i] = u_te[r * DH + d4 * 4 + c];
        teQ_i[i] = i_te[r * DH + d4 * 4 + c];
    }
}

// ---------------------------------------------------------------------------
// proj: h = feat @ W.T (fp32) + bf16 copy for gathers
// ---------------------------------------------------------------------------
__global__ __launch_bounds__(256) void proj_kernel(
    const float* __restrict__ feat, const float* __restrict__ W,
    float* __restrict__ h, ushort_t* __restrict__ hbf, int N)
{
    __shared__ float Wl[64 * 65];
    const int lane = threadIdx.x & 63;
    const int w = threadIdx.x >> 6;
    for (int i = threadIdx.x; i < 4096; i += 256)
        Wl[(i >> 6) * 65 + (i & 63)] = W[i];
    __syncthreads();
    int row0 = blockIdx.x * 32 + w * 8;
    for (int r = 0; r < 8; ++r) {
        int n = row0 + r;
        float fv = feat[n * DH + lane];
        float acc = 0.f;
        #pragma unroll
        for (int k = 0; k < DH; ++k)
            acc = fmaf(__shfl(fv, k), Wl[lane * 65 + k], acc);
        h[n * DH + lane] = acc;
        unsigned int ub = __float_as_uint(acc);
        ub += 0x7fffu + ((ub >> 16) & 1u);          // RNE to bf16
        hbf[n * DH + lane] = (ushort_t)(ub >> 16);
    }
}

// ---------------------------------------------------------------------------
// agg: 128-thread block = 2 waves = 2 independent nodes. No __syncthreads.
// Per-node LDS: bf16 mail [50][64] (XOR-swizzled 16B granules), dsth f32[64],
// slef f32[64]. Everything else register-resident via readlane/bpermute.
// ---------------------------------------------------------------------------
__global__ __launch_bounds__(128, 5) void agg_kernel(
    const ushort_t* __restrict__ h_src_bf,  // bf16 source embeddings
    const float*    __restrict__ h_dst,     // fp32 dst embeddings
    const float*    __restrict__ feat_dst,  // residual
    const int*      __restrict__ nbr,
    const int*      __restrict__ times,
    const float*    __restrict__ teQ,       // [16*50] float4 layout
    const float*    __restrict__ te_k,      // raw [50][64]
    const float*    __restrict__ gT4,       // packed gate
    float*          __restrict__ out)
{
    __shared__ __align__(16) ushort_t smail[2][KK * 64];
    __shared__ __align__(16) float    sdst[2][DH];
    __shared__ __align__(16) float    ssle[2][DH];

    const int wid  = threadIdx.x >> 6;
    const int lane = threadIdx.x & 63;
    const int n    = blockIdx.x * 2 + wid;
    char* mailb = (char*)smail[wid];

    // ---- P0: loads ----
    int my_t = 0, my_nb = 0;
    if (lane < KK) {
        my_t  = times[n * KK + lane];
        my_nb = nbr[n * KK + lane];
    }
    sdst[wid][lane] = h_dst[n * DH + lane];

    // ---- ranks: sro[k] = #{j<50: key_j > key_k} (keys unique) ----
    int key = my_t * 64 + lane;
    int sro = 0;
    #pragma unroll
    for (int j = 0; j < KK; ++j) {
        int kj = __builtin_amdgcn_readlane(key, j);
        sro += (kj > key) ? 1 : 0;
    }

    // ---- last = first argmax(times) ----
    int key2 = (lane < KK) ? (my_t * 64 + (63 - lane)) : -1;
    #pragma unroll
    for (int off = 32; off >= 1; off >>= 1) {
        int o = __shfl_xor(key2, off);
        key2 = key2 > o ? key2 : o;
    }
    const int last = __builtin_amdgcn_readfirstlane(63 - (key2 & 63));

    // ---- tp[r] = dot(te[r], dsth), lane = r ----
    float tp = 0.f;
    {
        int rr = (lane < KK) ? lane : 0;
        const float4* tq = (const float4*)teQ;
        #pragma unroll
        for (int d4 = 0; d4 < 16; ++d4) {
            float4 t4 = tq[d4 * KK + rr];
            float4 dv = *(const float4*)&sdst[wid][d4 * 4];
            tp += t4.x * dv.x + t4.y * dv.y + t4.z * dv.z + t4.w * dv.w;
        }
    }

    // ---- gather: 4 rows per iter, bf16 uint2 (8B) per lane, swizzled store ----
    {
        const int j = lane & 15;
        const int g = lane >> 4;
        #pragma unroll
        for (int kb = 0; kb < 13; ++kb) {
            int r  = kb * 4 + g;
            int rv = r < KK ? r : KK - 1;
            int idx = __builtin_amdgcn_ds_bpermute(rv << 2, my_nb);
            uint2 v = *(const uint2*)(h_src_bf + idx * DH + j * 4);
            int gran = (j >> 1) ^ (rv & 7);
            *(uint2*)(mailb + rv * 128 + gran * 16 + (j & 1) * 8) = v;
        }
    }

    // ---- slef = f32(mail[last]) ----
    {
        int gran = (lane >> 3) ^ (last & 7);
        ushort_t u = *(const ushort_t*)(mailb + last * 128 + gran * 16 + (lane & 7) * 2);
        ssle[wid][lane] = bflo((unsigned int)u << 0) , ssle[wid][lane] = __uint_as_float(((unsigned int)u) << 16);
    }

    // ---- dot phase, lane = k: e = dot(mail,dst), e1 = dot(mail,sle) ----
    const int kk = (lane < KK) ? lane : 0;
    float eacc = 0.f, e1acc = 0.f;
    {
        const int vbase = kk * 128 + ((kk & 7) << 4);
        #pragma unroll
        for (int d8 = 0; d8 < 8; ++d8) {
            uint4 m4 = *(const uint4*)(mailb + (vbase ^ (d8 << 4)));
            float4 da = *(const float4*)&sdst[wid][d8 * 8];
            float4 db = *(const float4*)&sdst[wid][d8 * 8 + 4];
            float4 sa = *(const float4*)&ssle[wid][d8 * 8];
            float4 sb = *(const float4*)&ssle[wid][d8 * 8 + 4];
            float m0 = bflo(m4.x), m1 = bfhi(m4.x);
            float m2 = bflo(m4.y), m3 = bfhi(m4.y);
            float m4f = bflo(m4.z), m5 = bfhi(m4.z);
            float m6 = bflo(m4.w), m7 = bfhi(m4.w);
            eacc  = fmaf(m0, da.x, eacc);  e1acc = fmaf(m0, sa.x, e1acc);
            eacc  = fmaf(m1, da.y, eacc);  e1acc = fmaf(m1, sa.y, e1acc);
            eacc  = fmaf(m2, da.z, eacc);  e1acc = fmaf(m2, sa.z, e1acc);
            eacc  = fmaf(m3, da.w, eacc);  e1acc = fmaf(m3, sa.w, e1acc);
            eacc  = fmaf(m4f, db.x, eacc); e1acc = fmaf(m4f, sb.x, e1acc);
            eacc  = fmaf(m5, db.y, eacc);  e1acc = fmaf(m5, sb.y, e1acc);
            eacc  = fmaf(m6, db.z, eacc);  e1acc = fmaf(m6, sb.z, e1acc);
            eacc  = fmaf(m7, db.w, eacc);  e1acc = fmaf(m7, sb.w, e1acc);
        }
    }

    // tp[sro[k]] pulled via bpermute
    float tps = __uint_as_float(__builtin_amdgcn_ds_bpermute(sro << 2, __float_as_uint(tp)));
    float e  = (lane < KK) ? (eacc + tps) * 0.125f : -INFINITY;
    float e1 = (lane < KK) ? e1acc * 0.125f        : -INFINITY;

    // ---- dual softmax over 50 lanes ----
    float m = e, m1 = e1;
    #pragma unroll
    for (int off = 32; off >= 1; off >>= 1) {
        m  = fmaxf(m,  __shfl_xor(m,  off));
        m1 = fmaxf(m1, __shfl_xor(m1, off));
    }
    float p  = (lane < KK) ? __expf(e - m)   : 0.f;
    float p1 = (lane < KK) ? __expf(e1 - m1) : 0.f;
    float s = p, s1 = p1;
    #pragma unroll
    for (int off = 32; off >= 1; off >>= 1) {
        s  += __shfl_xor(s,  off);
        s1 += __shfl_xor(s1, off);
    }
    float al  = p  * __builtin_amdgcn_rcpf(s);
    float al1 = p1 * __builtin_amdgcn_rcpf(s1);

    // ---- weighted sums, lane = d; alphas/sro via readlane (zero LDS) ----
    int voff[8];
    #pragma unroll
    for (int c = 0; c < 8; ++c)
        voff[c] = (((lane >> 3) ^ c) << 4) + (lane & 7) * 2;

    float hl = 0.f, hs = 0.f;
    #pragma unroll
    for (int k = 0; k < KK; ++k) {
        float a  = __uint_as_float(__builtin_amdgcn_readlane(__float_as_uint(al),  k));
        float a1 = __uint_as_float(__builtin_amdgcn_readlane(__float_as_uint(al1), k));
        int   sr = __builtin_amdgcn_readlane(sro, k);
        float t  = te_k[sr * DH + lane];
        ushort_t u = *(const ushort_t*)(mailb + k * 128 + voff[k & 7]);
        float mv = __uint_as_float(((unsigned int)u) << 16);
        hl = fmaf(a,  mv + t, hl);
        hs = fmaf(a1, mv,     hs);
    }

    // ---- gated output (cc overlays dead mail region) ----
    float* cc = (float*)mailb;
    cc[lane]      = hl;
    cc[DH + lane] = hs;
    float gacc = 0.f;
    const float4* g4 = (const float4*)gT4;
    #pragma unroll
    for (int jb = 0; jb < 32; ++jb) {
        float4 gv = g4[jb * 64 + lane];
        float4 c4 = *(const float4*)&cc[jb * 4];
        gacc = fmaf(gv.x, c4.x, gacc);
        gacc = fmaf(gv.y, c4.y, gacc);
        gacc = fmaf(gv.z, c4.z, gacc);
        gacc = fmaf(gv.w, c4.w, gacc);
    }
    float x = gacc + feat_dst[n * DH + lane];
    out[n * DH + lane] = x > 0.f ? x : (__expf(x) - 1.0f);
}

extern "C" void kernel_launch(void* const* d_in, const int* in_sizes, int n_in,
                              void* d_out, int out_size, void* d_ws, size_t ws_size,
                              hipStream_t stream) {
    const float* user_feat = (const float*)d_in[0];
    const float* item_feat = (const float*)d_in[1];
    const float* W_user    = (const float*)d_in[2];
    const float* W_item    = (const float*)d_in[3];
    const float* gate_u    = (const float*)d_in[4];
    const float* gate_i    = (const float*)d_in[5];
    const float* u_te      = (const float*)d_in[6];
    const float* u_te_k    = (const float*)d_in[7];
    const float* i_te      = (const float*)d_in[8];
    const float* i_te_k    = (const float*)d_in[9];
    const int*   user_nbr  = (const int*)d_in[10];
    const int*   item_nbr  = (const int*)d_in[11];
    const int*   user_time = (const int*)d_in[12];
    const int*   item_time = (const int*)d_in[13];

    float* ws      = (float*)d_ws;
    float* user_h  = ws;                          // 2097152
    float* item_h  = user_h + NU * DH;            // 1048576
    float* gT_u    = item_h + NI * DH;            // 8192
    float* gT_i    = gT_u + DH * 2 * DH;          // 8192
    float* teQ_u   = gT_i + DH * 2 * DH;          // 3200
    float* teQ_i   = teQ_u + 16 * KK * 4;         // 3200
    ushort_t* hbf_u = (ushort_t*)(teQ_i + 16 * KK * 4);   // NU*64 ushorts
    ushort_t* hbf_i = hbf_u + NU * DH;                     // NI*64 ushorts

    float* user_out = (float*)d_out;
    float* item_out = user_out + NU * DH;

    hipLaunchKernelGGL(prep_kernel, dim3(32), dim3(256), 0, stream,
                       gate_u, gate_i, u_te, i_te, gT_u, gT_i, teQ_u, teQ_i);
    hipLaunchKernelGGL(proj_kernel, dim3(NU / 32), dim3(256), 0, stream,
                       user_feat, W_user, user_h, hbf_u, NU);
    hipLaunchKernelGGL(proj_kernel, dim3(NI / 32), dim3(256), 0, stream,
                       item_feat, W_item, item_h, hbf_i, NI);
    hipLaunchKernelGGL(agg_kernel, dim3(NI / 2), dim3(128), 0, stream,
                       hbf_u, item_h, item_feat, item_nbr, item_time,
                       teQ_i, i_te_k, gT_i, item_out);
    hipLaunchKernelGGL(agg_kernel, dim3(NU / 2), dim3(128), 0, stream,
                       hbf_i, user_h, user_feat, user_nbr, user_time,
                       teQ_u, u_te_k, gT_u, user_out);
}